// Round 8
// baseline (297.602 us; speedup 1.0000x reference)
//
#include <hip/hip_runtime.h>
#include <math.h>

#define NN 20000
#define EE 400000
#define FIN 256
#define HH 16
#define CC 32
#define HC 512    // H*C per conv
#define HW 1024   // h12 row width (conv1 | conv2)
#define HIDN 128
#define OUTC 32
#define WT 1024   // wtc rows (W1^T | W2^T)
#define CAPD 64   // per-node LDS edge capacity (deg ~ Poisson(20), P(>64)~1e-16)

typedef unsigned short u16;
typedef unsigned long long u64;
typedef __attribute__((ext_vector_type(8))) short short8v;
typedef __attribute__((ext_vector_type(4))) float f32x4;

__device__ inline u16 f2bf(float f) {
  unsigned u = __builtin_bit_cast(unsigned, f);
  unsigned r = (u + 0x7fffu + ((u >> 16) & 1u)) >> 16;
  return (u16)r;
}
__device__ inline float bf2f(u16 b) {
  unsigned u = ((unsigned)b) << 16;
  return __builtin_bit_cast(float, u);
}

__device__ __forceinline__ void gload16(const u16* g, u16* l) {
  __builtin_amdgcn_global_load_lds(
      (const __attribute__((address_space(1))) unsigned int*)g,
      (__attribute__((address_space(3))) unsigned int*)l, 16, 0, 0);
}

// ------------------------------------------- merged converts + edge histogram
__global__ void k_prep_hist(const float* __restrict__ x, u16* __restrict__ xb,
                            const float* __restrict__ W1, const float* __restrict__ W2,
                            u16* __restrict__ wtc,
                            const float* __restrict__ L1, u16* __restrict__ lt1,
                            const float* __restrict__ L2, u16* __restrict__ lt2,
                            const int* __restrict__ ei, int* __restrict__ cur) {
  int b = blockIdx.x, t = threadIdx.x;
  if (b < 2500) {
    int i = b * 256 + t;
    float4 v0 = ((const float4*)x)[i * 2];
    float4 v1 = ((const float4*)x)[i * 2 + 1];
    short8v o;
    o[0] = (short)f2bf(v0.x); o[1] = (short)f2bf(v0.y);
    o[2] = (short)f2bf(v0.z); o[3] = (short)f2bf(v0.w);
    o[4] = (short)f2bf(v1.x); o[5] = (short)f2bf(v1.y);
    o[6] = (short)f2bf(v1.z); o[7] = (short)f2bf(v1.w);
    *(short8v*)(xb + (size_t)i * 8) = o;
  } else if (b < 3524) {
    int i = (b - 2500) * 256 + t;   // [1024][256]
    int n = i >> 8, k = i & 255;
    wtc[i] = f2bf(n < 512 ? W1[k * HC + n] : W2[k * HC + (n - 512)]);
  } else if (b < 3652) {
    int i = (b - 3524) * 256 + t;   // [128][256]
    int n = i >> 8, k = i & 255;
    lt1[i] = f2bf(L1[k * HIDN + n]);
  } else if (b < 3668) {
    int i = (b - 3652) * 256 + t;   // [32][128]
    int n = i >> 7, k = i & 127;
    lt2[i] = f2bf(L2[k * OUTC + n]);
  } else {
    int e = (b - 3668) * 256 + t;
    if (e < EE) {
      atomicAdd(&cur[ei[EE + e]], 1);       // conv1 aggregates at row1
      atomicAdd(&cur[NN + ei[e]], 1);       // conv2 aggregates at row0
    }
  }
}

__device__ void scan_one(int* cur, int* off, int* part) {
  const int t = threadIdx.x;
  const int CHK = 20;
  int base = t * CHK;
  int loc[CHK];
  int s = 0;
#pragma unroll
  for (int i = 0; i < CHK; ++i) {
    int idx = base + i;
    int v = (idx < NN) ? cur[idx] : 0;
    loc[i] = s;
    s += v;
  }
  part[t] = s;
  __syncthreads();
  for (int d = 1; d < 1024; d <<= 1) {
    int v2 = (t >= d) ? part[t - d] : 0;
    __syncthreads();
    part[t] += v2;
    __syncthreads();
  }
  int cbase = part[t] - s;
#pragma unroll
  for (int i = 0; i < CHK; ++i) {
    int idx = base + i;
    if (idx < NN) {
      int o = cbase + loc[i];
      off[idx] = o;
      cur[idx] = o;
    }
  }
  if (t == 1023) off[NN] = part[1023];
}

__global__ __launch_bounds__(1024) void k_scan(int* cur, int* off1, int* off2) {
  __shared__ int part[1024];
  if (blockIdx.x == 0) scan_one(cur, off1, part);
  else                 scan_one(cur + NN, off2, part);
}

// packed scatter: adjx1[p1] = (p2<<32)|s1  ;  adjx2[p2] = (p1<<32)|d1
__global__ void k_scatter(const int* __restrict__ ei, int* cur,
                          u64* __restrict__ adjx1, u64* __restrict__ adjx2) {
  int e = blockIdx.x * 256 + threadIdx.x;
  if (e < EE) {
    int s1 = ei[e], d1 = ei[EE + e];
    int p1 = atomicAdd(&cur[d1], 1);
    int p2 = atomicAdd(&cur[NN + s1], 1);
    adjx1[p1] = ((u64)(unsigned)p2 << 32) | (unsigned)s1;
    adjx2[p2] = ((u64)(unsigned)p1 << 32) | (unsigned)d1;
  }
}

// ------------------------- mega GEMM: h12 = x@[W1|W2]^T + fused a_s/a_d
// 1D grid 1256 = 157 bm x 8 bn, XCD-chunked.
__global__ __launch_bounds__(256) void k_gemm_big(const u16* __restrict__ A,
                                                  const u16* __restrict__ Bt,
                                                  const float* __restrict__ as1,
                                                  const float* __restrict__ ad1,
                                                  const float* __restrict__ as2,
                                                  const float* __restrict__ ad2,
                                                  u16* __restrict__ h12,
                                                  float* __restrict__ a_sA,
                                                  float* __restrict__ a_dA) {
  __shared__ u16 As[128 * 64];
  __shared__ u16 Bs[128 * 64];
  const int hw = blockIdx.x;
  const int logical = (hw & 7) * 157 + (hw >> 3);
  const int bm = (logical >> 3) * 128, bn = logical & 7;
  const int t = threadIdx.x;
  const int lane = t & 63, wave = t >> 6;
  const int wr = (wave >> 1) * 64, wc = (wave & 1) * 64;
  const int l15 = lane & 15, l4 = lane >> 4;
  const int rloc = lane >> 3;
  const int kc_src = (lane & 7) ^ rloc;
  const int K = FIN;

  f32x4 acc[4][4] = {};
  for (int k0 = 0; k0 < K; k0 += 64) {
    __syncthreads();
#pragma unroll
    for (int q = 0; q < 4; ++q) {
      const int rblk = q * 4 + wave;
      const int r = rblk * 8 + rloc;
      gload16(A + (size_t)(bm + r) * K + k0 + kc_src * 8, As + rblk * 512);
      gload16(Bt + (size_t)(bn * 128 + r) * K + k0 + kc_src * 8, Bs + rblk * 512);
    }
    __syncthreads();
#pragma unroll
    for (int kh = 0; kh < 2; ++kh) {
      const int kc = kh * 4 + l4;
      short8v af[4], bfr[4];
#pragma unroll
      for (int i = 0; i < 4; ++i) {
        int row = wr + i * 16 + l15;
        af[i] = *(const short8v*)(As + row * 64 + (kc ^ (row & 7)) * 8);
      }
#pragma unroll
      for (int j = 0; j < 4; ++j) {
        int row = wc + j * 16 + l15;
        bfr[j] = *(const short8v*)(Bs + row * 64 + (kc ^ (row & 7)) * 8);
      }
#pragma unroll
      for (int i = 0; i < 4; ++i)
#pragma unroll
        for (int j = 0; j < 4; ++j)
          acc[i][j] = __builtin_amdgcn_mfma_f32_16x16x32_bf16(af[i], bfr[j], acc[i][j], 0, 0, 0);
    }
  }

  const int conv = bn >> 2;
#pragma unroll
  for (int i = 0; i < 4; ++i)
#pragma unroll
    for (int j = 0; j < 4; ++j)
#pragma unroll
      for (int r = 0; r < 4; ++r) {
        int row = bm + wr + i * 16 + l4 * 4 + r;
        if (row >= NN) continue;
        int colb = bn * 128 + wc + j * 16 + l15;
        h12[(size_t)row * HW + colb] = f2bf(acc[i][j][r]);
      }

  float asv[4], adv[4];
#pragma unroll
  for (int j = 0; j < 4; ++j) {
    int lc = (bn & 3) * 128 + wc + j * 16 + l15;
    int hh = lc >> 5, c = lc & 31;
    asv[j] = (conv ? as2 : as1)[hh * CC + c];
    adv[j] = (conv ? ad2 : ad1)[hh * CC + c];
  }
  const int hA = (bn & 3) * 4 + (wc >> 5);
  float* aS = a_sA + (size_t)conv * NN * HH;
  float* aD = a_dA + (size_t)conv * NN * HH;
#pragma unroll
  for (int i = 0; i < 4; ++i)
#pragma unroll
    for (int r = 0; r < 4; ++r) {
      float sAs = acc[i][0][r] * asv[0] + acc[i][1][r] * asv[1];
      float sAd = acc[i][0][r] * adv[0] + acc[i][1][r] * adv[1];
      float sBs = acc[i][2][r] * asv[2] + acc[i][3][r] * asv[3];
      float sBd = acc[i][2][r] * adv[2] + acc[i][3][r] * adv[3];
#pragma unroll
      for (int m = 1; m < 16; m <<= 1) {
        sAs += __shfl_xor(sAs, m);
        sAd += __shfl_xor(sAd, m);
        sBs += __shfl_xor(sBs, m);
        sBd += __shfl_xor(sBd, m);
      }
      int row = bm + wr + i * 16 + l4 * 4 + r;
      if (l15 == 0 && row < NN) {
        *(float2*)(aS + (size_t)row * HH + hA) = make_float2(sAs, sBs);
        *(float2*)(aD + (size_t)row * HH + hA) = make_float2(sAd, sBd);
      }
    }
}

// --------------------------- self path: out3 = elu(elu(x@lin1+b)@lin2+b)
__global__ __launch_bounds__(256) void k_self(const u16* __restrict__ A,
                                              const u16* __restrict__ lt1,
                                              const u16* __restrict__ lt2,
                                              const float* __restrict__ lin1_b,
                                              const float* __restrict__ lin2_b,
                                              float* __restrict__ outp) {
  __shared__ u16 smem[128 * 136];
  u16* As = smem;
  u16* Bs = smem + 128 * 64;
  const int t = threadIdx.x;
  const int lane = t & 63, wave = t >> 6;
  const int wr = (wave >> 1) * 64, wc = (wave & 1) * 64;
  const int bm = blockIdx.x * 128;
  const int l15 = lane & 15, l4 = lane >> 4;
  const int rloc = lane >> 3;
  const int kc_src = (lane & 7) ^ rloc;
  const int K = FIN;

  f32x4 acc[4][4] = {};
  for (int k0 = 0; k0 < K; k0 += 64) {
    __syncthreads();
#pragma unroll
    for (int q = 0; q < 4; ++q) {
      const int rblk = q * 4 + wave;
      const int r = rblk * 8 + rloc;
      gload16(A + (size_t)(bm + r) * K + k0 + kc_src * 8, As + rblk * 512);
      gload16(lt1 + (size_t)r * K + k0 + kc_src * 8, Bs + rblk * 512);
    }
    __syncthreads();
#pragma unroll
    for (int kh = 0; kh < 2; ++kh) {
      const int kc = kh * 4 + l4;
      short8v af[4], bfr[4];
#pragma unroll
      for (int i = 0; i < 4; ++i) {
        int row = wr + i * 16 + l15;
        af[i] = *(const short8v*)(As + row * 64 + (kc ^ (row & 7)) * 8);
      }
#pragma unroll
      for (int j = 0; j < 4; ++j) {
        int row = wc + j * 16 + l15;
        bfr[j] = *(const short8v*)(Bs + row * 64 + (kc ^ (row & 7)) * 8);
      }
#pragma unroll
      for (int i = 0; i < 4; ++i)
#pragma unroll
        for (int j = 0; j < 4; ++j)
          acc[i][j] = __builtin_amdgcn_mfma_f32_16x16x32_bf16(af[i], bfr[j], acc[i][j], 0, 0, 0);
    }
  }
  __syncthreads();
#pragma unroll
  for (int i = 0; i < 4; ++i)
#pragma unroll
    for (int j = 0; j < 4; ++j)
#pragma unroll
      for (int r = 0; r < 4; ++r) {
        int row = wr + i * 16 + l4 * 4 + r;
        int col = wc + j * 16 + l15;
        float v = acc[i][j][r] + lin1_b[col];
        v = v > 0.f ? v : (expf(v) - 1.f);
        smem[row * 136 + col] = f2bf(v);
      }
  __syncthreads();
  f32x4 acc2[2][2] = {};
#pragma unroll
  for (int kk = 0; kk < 4; ++kk) {
    short8v af[2], bfr[2];
#pragma unroll
    for (int i = 0; i < 2; ++i)
      af[i] = *(const short8v*)(smem + (wave * 32 + i * 16 + l15) * 136 + kk * 32 + l4 * 8);
#pragma unroll
    for (int j = 0; j < 2; ++j)
      bfr[j] = *(const short8v*)(lt2 + (size_t)(j * 16 + l15) * 128 + kk * 32 + l4 * 8);
#pragma unroll
    for (int i = 0; i < 2; ++i)
#pragma unroll
      for (int j = 0; j < 2; ++j)
        acc2[i][j] = __builtin_amdgcn_mfma_f32_16x16x32_bf16(af[i], bfr[j], acc2[i][j], 0, 0, 0);
  }
#pragma unroll
  for (int i = 0; i < 2; ++i)
#pragma unroll
    for (int j = 0; j < 2; ++j)
#pragma unroll
      for (int r = 0; r < 4; ++r) {
        int row = bm + wave * 32 + i * 16 + l4 * 4 + r;
        int col = j * 16 + l15;
        if (row < NN) {
          float v = acc2[i][j][r] + lin2_b[col];
          v = v > 0.f ? v : (expf(v) - 1.f);
          outp[(size_t)row * OUTC + col] = v;
        }
      }
}

// --------------- phase A: dst-grouped softmax -> coef[p] SEQUENTIAL (dst-order)
__global__ __launch_bounds__(256) void k_phaseA(const u64* __restrict__ adjx1,
                                                const int* __restrict__ off1,
                                                const u64* __restrict__ adjx2,
                                                const int* __restrict__ off2,
                                                const float* __restrict__ a_sA,
                                                const float* __restrict__ a_dA,
                                                u16* __restrict__ coefA,
                                                u16* __restrict__ coefB) {
  __shared__ float exs[4][CAPD * 16];
  const int wv = threadIdx.x >> 6, lane = threadIdx.x & 63;
  const int gid = blockIdx.x * 4 + wv;
  const int conv = gid >= NN;
  const int node = gid - conv * NN;
  const u64* __restrict__ adjx = conv ? adjx2 : adjx1;
  const int* __restrict__ off = conv ? off2 : off1;
  u16* __restrict__ coef = conv ? coefB : coefA;
  const float* __restrict__ a_s = a_sA + (size_t)conv * NN * HH;
  const float* __restrict__ a_d = a_dA + (size_t)conv * NN * HH;
  float* exw = exs[wv];
  const int e0 = off[node], e1 = off[node + 1];
  if (e0 == e1) return;

  const int ha = lane & 15, j = lane >> 4;
  const float adh = a_d[node * HH + ha];
  float mx = -INFINITY;
  for (int p = e0 + j; p < e1; p += 4) {
    int s = (int)(unsigned)adjx[p];
    float a = a_s[s * HH + ha] + adh;
    a = a > 0.f ? a : 0.2f * a;
    int q = p - e0;
    if (q < CAPD) exw[q * 16 + ha] = a;
    mx = fmaxf(mx, a);
  }
  mx = fmaxf(mx, __shfl_xor(mx, 16));
  mx = fmaxf(mx, __shfl_xor(mx, 32));
  float sum = 0.f;
  for (int p = e0 + j; p < e1; p += 4) {
    int q = p - e0;
    float a;
    if (q < CAPD) {
      a = exw[q * 16 + ha];
    } else {
      int s = (int)(unsigned)adjx[p];
      a = a_s[s * HH + ha] + adh;
      a = a > 0.f ? a : 0.2f * a;
    }
    float e = __expf(a - mx);
    if (q < CAPD) exw[q * 16 + ha] = e;
    sum += e;
  }
  sum += __shfl_xor(sum, 16);
  sum += __shfl_xor(sum, 32);
  const float inv16 = 1.f / ((sum + 1e-16f) * 16.f);
  for (int p = e0 + j; p < e1; p += 4) {
    int q = p - e0;
    float e;
    if (q < CAPD) {
      e = exw[q * 16 + ha];
    } else {
      int s = (int)(unsigned)adjx[p];
      float a = a_s[s * HH + ha] + adh;
      a = a > 0.f ? a : 0.2f * a;
      e = __expf(a - mx);
    }
    coef[(size_t)p * 16 + ha] = f2bf(e * inv16);
  }
}

// --------------- scatterv: src-grouped; gather coef via adjx-high, stream h,
// write vbuf sequential. Both convs in one grid.
__global__ __launch_bounds__(256) void k_scatterv(const int* __restrict__ off1,
                                                  const u64* __restrict__ adjx1,
                                                  const int* __restrict__ off2,
                                                  const u64* __restrict__ adjx2,
                                                  const u16* __restrict__ coefA,
                                                  const u16* __restrict__ coefB,
                                                  const u16* __restrict__ h12,
                                                  u16* __restrict__ vbufA,
                                                  u16* __restrict__ vbufB) {
  __shared__ u16 hs[4][512];
  const int wv = threadIdx.x >> 6, lane = threadIdx.x & 63;
  const int gid = blockIdx.x * 4 + wv;
  const int conv = gid >= NN;
  const int s = gid - conv * NN;
  // conv1: src-groups off2 (by row0), partner pos from adjx2 high, coefA, h half0
  // conv2: src-groups off1 (by row1), partner pos from adjx1 high, coefB, h half1
  const int* __restrict__ offS = conv ? off1 : off2;
  const u64* __restrict__ adjx = conv ? adjx1 : adjx2;
  const u16* __restrict__ coef = conv ? coefB : coefA;
  u16* __restrict__ vbuf = conv ? vbufB : vbufA;
  const int e0 = offS[s], e1 = offS[s + 1];
  if (e0 == e1) return;
  const u16* hp = h12 + (size_t)s * HW + conv * HC;
  *(short8v*)&hs[wv][lane * 8] = *(const short8v*)(hp + lane * 8);
  __builtin_amdgcn_wave_barrier();
  __asm__ volatile("" ::: "memory");
  const int c = lane & 31, ep = lane >> 5;
  float hreg[16];
#pragma unroll
  for (int h = 0; h < 16; ++h) hreg[h] = bf2f(hs[wv][h * 32 + c]);
  for (int q = e0 + ep; q < e1; q += 2) {
    int p = (int)(adjx[q] >> 32);
    short8v c0 = *(const short8v*)(coef + (size_t)p * 16);
    short8v c1 = *(const short8v*)(coef + (size_t)p * 16 + 8);
    float v = 0.f;
#pragma unroll
    for (int h = 0; h < 8; ++h) v = fmaf(bf2f((u16)c0[h]), hreg[h], v);
#pragma unroll
    for (int h = 0; h < 8; ++h) v = fmaf(bf2f((u16)c1[h]), hreg[h + 8], v);
    vbuf[(size_t)q * 32 + c] = f2bf(v);
  }
}

// --------------- pass2: dst-grouped gather of vbuf (64B/edge), sum, bias+elu
__global__ __launch_bounds__(256) void k_pass2(const int* __restrict__ off1,
                                               const u64* __restrict__ adjx1,
                                               const int* __restrict__ off2,
                                               const u64* __restrict__ adjx2,
                                               const u16* __restrict__ vbufA,
                                               const u16* __restrict__ vbufB,
                                               const float* __restrict__ b1,
                                               const float* __restrict__ b2,
                                               float* __restrict__ out) {
  const int wv = threadIdx.x >> 6, lane = threadIdx.x & 63;
  const int gid = blockIdx.x * 4 + wv;
  const int conv = gid >= NN;
  const int d = gid - conv * NN;
  const int* __restrict__ off = conv ? off2 : off1;
  const u64* __restrict__ adjx = conv ? adjx2 : adjx1;
  const u16* __restrict__ vbuf = conv ? vbufB : vbufA;
  const float* __restrict__ bias = conv ? b2 : b1;
  float* __restrict__ outp = out + (size_t)conv * NN * OUTC;
  const int c = lane & 31, ep = lane >> 5;
  const int e0 = off[d], e1 = off[d + 1];
  float a0 = 0.f, a1 = 0.f;
  int p = e0 + ep;
  for (; p + 2 < e1; p += 4) {
    int q0 = (int)(adjx[p] >> 32), q1 = (int)(adjx[p + 2] >> 32);
    a0 += bf2f(vbuf[(size_t)q0 * 32 + c]);
    a1 += bf2f(vbuf[(size_t)q1 * 32 + c]);
  }
  if (p < e1) a0 += bf2f(vbuf[(size_t)(adjx[p] >> 32) * 32 + c]);
  float acc = a0 + a1;
  acc += __shfl_xor(acc, 32);
  if (lane < 32) {
    float v = acc + bias[c];
    v = v > 0.f ? v : (expf(v) - 1.f);
    outp[(size_t)d * OUTC + c] = v;
  }
}

// ---------------------------------------------------------------- launch
extern "C" void kernel_launch(void* const* d_in, const int* in_sizes, int n_in,
                              void* d_out, int out_size, void* d_ws, size_t ws_size,
                              hipStream_t stream) {
  const float* x = (const float*)d_in[0];
  const int* ei = (const int*)d_in[1];
  const float* W1 = (const float*)d_in[2];
  const float* att_src1 = (const float*)d_in[3];
  const float* att_dst1 = (const float*)d_in[4];
  const float* b1 = (const float*)d_in[5];
  const float* W2 = (const float*)d_in[6];
  const float* att_src2 = (const float*)d_in[7];
  const float* att_dst2 = (const float*)d_in[8];
  const float* b2 = (const float*)d_in[9];
  const float* lin1_w = (const float*)d_in[10];
  const float* lin1_b = (const float*)d_in[11];
  const float* lin2_w = (const float*)d_in[12];
  const float* lin2_b = (const float*)d_in[13];
  float* out = (float*)d_out;  // [x_in | x_out | x_self], each N*32

  char* w = (char*)d_ws;
  u16* h12 = (u16*)w;       w += (size_t)NN * HW * 2;      // 40.96 MB
  u16* x_bf = (u16*)w;      w += (size_t)NN * FIN * 2;     // 10.24 MB
  u16* wtc = (u16*)w;       w += (size_t)WT * FIN * 2;     // 0.52 MB
  u16* lt1 = (u16*)w;       w += (size_t)HIDN * FIN * 2;
  u16* lt2 = (u16*)w;       w += (size_t)OUTC * HIDN * 2;
  u16* coefA = (u16*)w;     w += (size_t)EE * HH * 2;      // 12.8 MB
  u16* coefB = (u16*)w;     w += (size_t)EE * HH * 2;      // 12.8 MB
  u16* vbufA = (u16*)w;     w += (size_t)EE * OUTC * 2;    // 25.6 MB
  u16* vbufB = (u16*)w;     w += (size_t)EE * OUTC * 2;    // 25.6 MB
  float* a_sA = (float*)w;  w += (size_t)2 * NN * HH * 4;  // 2.56 MB
  float* a_dA = (float*)w;  w += (size_t)2 * NN * HH * 4;
  int* off1 = (int*)w;      w += (size_t)(NN + 1) * 4;
  int* off2 = (int*)w;      w += (size_t)(NN + 1) * 4;
  int* cur = (int*)w;       w += (size_t)2 * NN * 4;
  u64* adjx1 = (u64*)w;     w += (size_t)EE * 8;           // 3.2 MB
  u64* adjx2 = (u64*)w;     w += (size_t)EE * 8;           // 3.2 MB

  const int EB = (EE + 255) / 256;  // 1563

  // CSR build + converts
  hipMemsetAsync(cur, 0, (size_t)2 * NN * 4, stream);
  k_prep_hist<<<3668 + EB, 256, 0, stream>>>(x, x_bf, W1, W2, wtc, lin1_w, lt1,
                                             lin2_w, lt2, ei, cur);
  k_scan<<<2, 1024, 0, stream>>>(cur, off1, off2);
  k_scatter<<<EB, 256, 0, stream>>>(ei, cur, adjx1, adjx2);

  // GEMMs
  k_gemm_big<<<1256, 256, 0, stream>>>(x_bf, wtc, att_src1, att_dst1,
                                       att_src2, att_dst2, h12, a_sA, a_dA);
  k_self<<<157, 256, 0, stream>>>(x_bf, lt1, lt2, lin1_b, lin2_b,
                                  out + (size_t)2 * NN * OUTC);

  // edge pipeline (both convs per launch)
  k_phaseA<<<2 * (NN / 4), 256, 0, stream>>>(adjx1, off1, adjx2, off2,
                                             a_sA, a_dA, coefA, coefB);
  k_scatterv<<<2 * (NN / 4), 256, 0, stream>>>(off1, adjx1, off2, adjx2,
                                               coefA, coefB, h12, vbufA, vbufB);
  k_pass2<<<2 * (NN / 4), 256, 0, stream>>>(off1, adjx1, off2, adjx2,
                                            vbufA, vbufB, b1, b2, out);
}